// Round 5
// baseline (165.165 us; speedup 1.0000x reference)
//
#include <hip/hip_runtime.h>

#define Dm  128
#define K1  64
#define TE3 256       // edges per block: 4 waves x 4 quarters x 16 edges
#define LUT_ROWS 8    // LUT rows per prep block -> T/8 blocks (full-GPU parallel)

typedef _Float16 h8 __attribute__((ext_vector_type(8)));
typedef __attribute__((address_space(1))) const void gas1;
typedef __attribute__((address_space(3))) void las3;

__device__ __forceinline__ float ssp(float x) {
    return __logf(1.0f + __expf(x)) - 0.69314718056f;
}

__device__ __forceinline__ unsigned int pack_h2f(float a, float b) {
    _Float16 v[2] = {(_Float16)a, (_Float16)b};
    unsigned int u;
    __builtin_memcpy(&u, v, 4);
    return u;
}

// Fused prep, 256 threads/block:
//   [0, LUTB):        NN filter LUT (midpoint), 8 rows/block, 4 rows/thread
//   [LUTB, +ZB):      zero d_out
//   [LUTB+ZB, +CB):   convert atom_features f32 -> f16
__global__ void prep_all(const float* __restrict__ centers,
                         const float* __restrict__ gamma,
                         const float* __restrict__ W1,
                         const float* __restrict__ b1,
                         const float* __restrict__ W2,
                         const float* __restrict__ b2,
                         const float* __restrict__ af,
                         _Float16* __restrict__ tab,
                         _Float16* __restrict__ afh,
                         float* __restrict__ out,
                         int T, int LUTB, int ZB, int CB, int NATD) {
    __shared__ float rbf[LUT_ROWS][K1];    // 2 KB
    __shared__ float h1s[LUT_ROWS][Dm];    // 4 KB
    const int blk = blockIdx.x;
    const int t = threadIdx.x;             // 0..255

    if (blk < LUTB) {
        const int r0 = blk * LUT_ROWS;
        const float invT = 1.0f / (float)T;
        // 512 entries, 256 threads -> 2 strided iterations
        #pragma unroll
        for (int i = t; i < LUT_ROWS * K1; i += 256) {
            int r = i >> 6, k = i & 63;
            float d = ((float)(r0 + r) + 0.5f) * invT;   // midpoint sample
            float diff = d - centers[k];
            rbf[r][k] = __expf(-gamma[k] * diff * diff);
        }
        __syncthreads();
        const int ch = t & 127;
        const int rb = (t >> 7) * 4;       // rows [rb, rb+4)
        float acc[4];
        {
            float b = b1[ch];
            #pragma unroll
            for (int r = 0; r < 4; ++r) acc[r] = b;
        }
        #pragma unroll 4
        for (int k = 0; k < K1; ++k) {
            float w = W1[k * Dm + ch];
            #pragma unroll
            for (int r = 0; r < 4; ++r) acc[r] = fmaf(rbf[rb + r][k], w, acc[r]);
        }
        #pragma unroll
        for (int r = 0; r < 4; ++r) h1s[rb + r][ch] = ssp(acc[r]);
        __syncthreads();
        {
            float b = b2[ch];
            #pragma unroll
            for (int r = 0; r < 4; ++r) acc[r] = b;
        }
        #pragma unroll 4
        for (int k = 0; k < Dm; ++k) {
            float w = W2[k * Dm + ch];
            #pragma unroll
            for (int r = 0; r < 4; ++r) acc[r] = fmaf(h1s[rb + r][k], w, acc[r]);
        }
        #pragma unroll
        for (int r = 0; r < 4; ++r)
            tab[(size_t)(r0 + rb + r) * Dm + ch] = (_Float16)ssp(acc[r]);
    } else if (blk < LUTB + ZB) {
        const int b = blk - LUTB;
        float4* o4 = (float4*)out;
        const int n4 = NATD >> 2;
        const float4 z = make_float4(0.f, 0.f, 0.f, 0.f);
        for (int i = b * 256 + t; i < n4; i += ZB * 256) o4[i] = z;
    } else if (CB > 0) {
        const int b = blk - LUTB - ZB;
        const float4* a4 = (const float4*)af;
        uint2* d4 = (uint2*)afh;
        const int n4 = NATD >> 2;
        for (int i = b * 256 + t; i < n4; i += CB * 256) {
            float4 v = a4[i];
            uint2 st;
            st.x = pack_h2f(v.x, v.y);
            st.y = pack_h2f(v.z, v.w);
            d4[i] = st;
        }
    }
}

// Main: 16 lanes per edge. Each quarter-wave owns a contiguous 16-edge sorted
// range. Flush transposes through LDS so each atomic instr writes one 64B line.
//
// History (latency-bound: 18% VALU / 32% fabric / MFMA 0 / in-flight ~13 lines/CU):
//   R0: (256,4)  61.3 us, VGPR 56.
//   R1: (256,8)  forced VGPR 32 -> spills, 147 us. Revert.
//   R2: LDS-accumulate: global atomics NOT the wall; LDS-RMW cost more, 83 us. Revert.
//   R3: (256) no-min: better scheduling, 53.0 us. Keep.
//   R4: sched_barrier load/consume fence: VGPR stayed 56 -> RA re-serialized
//       gathers anyway, 53.3 us. VGPR-held MLP is a dead end.
//   R5 (this): afh gather via __builtin_amdgcn_global_load_lds DMA. Data
//       bypasses VGPRs: per wave, 16 DMA instrs put all 64 av rows (16 KB)
//       in flight, ONE vmcnt(0), then consume from LDS (ds_read_b128) while
//       tab (L2 LUT) pipelines in VGPRs. In-flight bytes/CU ~1KB -> ~128KB.
//       LDS 76KB/block -> 2 blocks/CU (occupancy drop expected & accepted).
template<bool AF16>
__global__ __launch_bounds__(256) void cfconv_v9(
    const float* __restrict__ af,
    const _Float16* __restrict__ afh,
    const float* __restrict__ distances,
    const int*   __restrict__ idx_j,
    const int*   __restrict__ seg_i,
    const _Float16* __restrict__ tab,
    float* __restrict__ out, int T)
{
    __shared__ int4     meta[TE3];         // {idx_j, seg_i, lut row, pad}  4 KB
    __shared__ _Float16 avs[4][16][512];   // [wave][k][4 rows x 256B]     64 KB
    __shared__ float    xscr[16 * 128];    // per-quarter transpose scratch 8 KB
    const int t = threadIdx.x;
    const long eb = (long)blockIdx.x * TE3;

    {
        float d = distances[eb + t];
        int iv = (int)(d * (float)T);
        iv = iv < 0 ? 0 : (iv > T - 1 ? T - 1 : iv);
        meta[t] = make_int4(idx_j[eb + t], seg_i[eb + t], iv, 0);
    }
    __syncthreads();

    const int lane = t & 63;
    const int g    = t >> 6;            // wave id
    const int eq   = lane >> 4;         // quarter: contiguous 16-edge subrange
    const int li   = lane & 15;
    const int c8   = li * 8;            // 8-channel slot owned during gather
    const int m0   = g * 64 + eq * 16;
    float* xp = &xscr[(t >> 4) * 128];  // this quarter's 512B scratch

    // ---- av staging: 16 global->LDS DMA instrs, all rows of this wave's 64
    // edges in flight at once. Lane (eq,li) fetches 16B of quarter eq's k-th
    // edge row; DMA writes lds_base + lane*16 = eq*256 + li*16 -> row-major
    // by construction. No VGPRs consumed; vmcnt carries 16 outstanding.
    if (AF16) {
        #pragma unroll
        for (int k = 0; k < 16; ++k) {
            const int idx = meta[m0 + k].x;
            const _Float16* src = &afh[(size_t)idx * Dm + c8];
            __builtin_amdgcn_global_load_lds((gas1*)src, (las3*)&avs[g][k][0],
                                             16, 0, 0);
        }
        // Single bulk wait: DMA writes to this wave's LDS region have landed.
        // No atomics are outstanding yet, so vmcnt(0) waits only the DMAs.
        asm volatile("s_waitcnt vmcnt(0)" ::: "memory");
        __builtin_amdgcn_sched_barrier(0);
    }

    int cur = meta[m0].y;               // quarter-uniform (held per-lane)
    float s[8];
    #pragma unroll
    for (int i = 0; i < 8; ++i) s[i] = 0.f;

    // quarter-lockstep flush: stage 16x8 block in LDS, read transposed so
    // atomic instr j covers out[cur*128 + j*16 + (0..15)] = one 64B line.
    auto flush = [&](int seg) {
        *(float4*)&xp[c8]     = make_float4(s[0], s[1], s[2], s[3]);
        *(float4*)&xp[c8 + 4] = make_float4(s[4], s[5], s[6], s[7]);
        float* op = &out[(size_t)seg * Dm];
        #pragma unroll
        for (int j = 0; j < 8; ++j)
            atomicAdd(op + j * 16 + li, xp[j * 16 + li]);
    };

    #pragma unroll
    for (int b = 0; b < 2; ++b) {
        h8  tb[8], av[8];
        int sg[8];
        #pragma unroll
        for (int j = 0; j < 8; ++j) {
            int4 md = meta[m0 + b * 8 + j];
            sg[j] = md.y;
            tb[j] = *(const h8*)&tab[(size_t)md.z * Dm + c8];
            if (AF16) {
                // staged row: [wave][edge k][eq*256B + li*16B]
                av[j] = *(const h8*)&avs[g][b * 8 + j][eq * 128 + c8];
            } else {
                float4 a0 = *(const float4*)&af[(size_t)md.x * Dm + c8];
                float4 a1 = *(const float4*)&af[(size_t)md.x * Dm + c8 + 4];
                av[j][0] = (_Float16)a0.x; av[j][1] = (_Float16)a0.y;
                av[j][2] = (_Float16)a0.z; av[j][3] = (_Float16)a0.w;
                av[j][4] = (_Float16)a1.x; av[j][5] = (_Float16)a1.y;
                av[j][6] = (_Float16)a1.z; av[j][7] = (_Float16)a1.w;
            }
        }
        #pragma unroll
        for (int j = 0; j < 8; ++j) {
            if (sg[j] != cur) {          // quarter-divergent, rare (~2/16)
                flush(cur);
                #pragma unroll
                for (int i = 0; i < 8; ++i) s[i] = 0.f;
                cur = sg[j];
            }
            #pragma unroll
            for (int i = 0; i < 8; ++i)   // v_fma_mix_f32: f16*f16 + f32
                s[i] = fmaf((float)tb[j][i], (float)av[j][i], s[i]);
        }
    }
    flush(cur);
}

extern "C" void kernel_launch(void* const* d_in, const int* in_sizes, int n_in,
                              void* d_out, int out_size, void* d_ws, size_t ws_size,
                              hipStream_t stream) {
    const float* atom_features = (const float*)d_in[0];
    const float* distances     = (const float*)d_in[1];
    const int*   idx_j         = (const int*)d_in[2];
    const int*   seg_i         = (const int*)d_in[3];
    const float* centers       = (const float*)d_in[4];
    const float* gamma         = (const float*)d_in[5];
    const float* W1            = (const float*)d_in[6];
    const float* b1            = (const float*)d_in[7];
    const float* W2            = (const float*)d_in[8];
    const float* b2            = (const float*)d_in[9];

    const int E    = in_sizes[1];   // 800000, divisible by TE3=256
    const int NATD = out_size;      // 50000*128
    float* out = (float*)d_out;

    // ws: [tab: T*Dm*2 bytes][afh: NATD*2 bytes]
    int T; bool af16;
    const size_t afh_bytes = (size_t)NATD * 2;
    if      (ws_size >= (size_t)2048 * Dm * 2 + afh_bytes) { T = 2048; af16 = true;  }
    else if (ws_size >= (size_t)2048 * Dm * 2)             { T = 2048; af16 = false; }
    else                                                   { T = 512;  af16 = false; }

    _Float16* tab = (_Float16*)d_ws;
    _Float16* afh = (_Float16*)((char*)d_ws + (size_t)T * Dm * 2);

    const int LUTB = T / LUT_ROWS;      // 256 blocks at T=2048
    const int ZB = 256;
    const int CB = af16 ? 256 : 0;
    prep_all<<<LUTB + ZB + CB, 256, 0, stream>>>(
        centers, gamma, W1, b1, W2, b2, atom_features,
        tab, afh, out, T, LUTB, ZB, CB, NATD);

    if (af16)
        cfconv_v9<true><<<E / TE3, 256, 0, stream>>>(
            atom_features, afh, distances, idx_j, seg_i, tab, out, T);
    else
        cfconv_v9<false><<<E / TE3, 256, 0, stream>>>(
            atom_features, afh, distances, idx_j, seg_i, tab, out, T);
}

// Round 6
// 147.812 us; speedup vs baseline: 1.1174x; 1.1174x over previous
//
#include <hip/hip_runtime.h>

#define Dm  128
#define K1  64
#define LUT_ROWS 8    // LUT rows per prep block -> T/8 blocks (full-GPU parallel)
#define CAPE 512      // staged edges per block (16 segments ~ 256 +- 16 edges)
#define SEGB 16       // segments per block (one per 16-lane quarter)

typedef _Float16 h8 __attribute__((ext_vector_type(8)));

__device__ __forceinline__ float ssp(float x) {
    return __logf(1.0f + __expf(x)) - 0.69314718056f;
}

__device__ __forceinline__ unsigned int pack_h2f(float a, float b) {
    _Float16 v[2] = {(_Float16)a, (_Float16)b};
    unsigned int u;
    __builtin_memcpy(&u, v, 4);
    return u;
}

// Fused prep, 256 threads/block:
//   [0, LUTB):            NN filter LUT (midpoint), 8 rows/block
//   [LUTB, +CB):          convert atom_features f32 -> f16
//   [LUTB+CB, +RB):       row_ptr build (seg_i is sorted -> scatter boundaries)
// NOTE: no out-zeroing pass anymore — v10 writes every out row exactly once.
__global__ void prep_all(const float* __restrict__ centers,
                         const float* __restrict__ gamma,
                         const float* __restrict__ W1,
                         const float* __restrict__ b1,
                         const float* __restrict__ W2,
                         const float* __restrict__ b2,
                         const float* __restrict__ af,
                         const int*   __restrict__ seg_i,
                         _Float16* __restrict__ tab,
                         _Float16* __restrict__ afh,
                         int* __restrict__ rp,
                         int T, int LUTB, int CB, int RB,
                         int NATD, int E, int NAT) {
    __shared__ float rbf[LUT_ROWS][K1];    // 2 KB
    __shared__ float h1s[LUT_ROWS][Dm];    // 4 KB
    const int blk = blockIdx.x;
    const int t = threadIdx.x;             // 0..255

    if (blk < LUTB) {
        const int r0 = blk * LUT_ROWS;
        const float invT = 1.0f / (float)T;
        #pragma unroll
        for (int i = t; i < LUT_ROWS * K1; i += 256) {
            int r = i >> 6, k = i & 63;
            float d = ((float)(r0 + r) + 0.5f) * invT;   // midpoint sample
            float diff = d - centers[k];
            rbf[r][k] = __expf(-gamma[k] * diff * diff);
        }
        __syncthreads();
        const int ch = t & 127;
        const int rb = (t >> 7) * 4;       // rows [rb, rb+4)
        float acc[4];
        {
            float b = b1[ch];
            #pragma unroll
            for (int r = 0; r < 4; ++r) acc[r] = b;
        }
        #pragma unroll 4
        for (int k = 0; k < K1; ++k) {
            float w = W1[k * Dm + ch];
            #pragma unroll
            for (int r = 0; r < 4; ++r) acc[r] = fmaf(rbf[rb + r][k], w, acc[r]);
        }
        #pragma unroll
        for (int r = 0; r < 4; ++r) h1s[rb + r][ch] = ssp(acc[r]);
        __syncthreads();
        {
            float b = b2[ch];
            #pragma unroll
            for (int r = 0; r < 4; ++r) acc[r] = b;
        }
        #pragma unroll 4
        for (int k = 0; k < Dm; ++k) {
            float w = W2[k * Dm + ch];
            #pragma unroll
            for (int r = 0; r < 4; ++r) acc[r] = fmaf(h1s[rb + r][k], w, acc[r]);
        }
        #pragma unroll
        for (int r = 0; r < 4; ++r)
            tab[(size_t)(r0 + rb + r) * Dm + ch] = (_Float16)ssp(acc[r]);
    } else if (blk < LUTB + CB) {
        const int b = blk - LUTB;
        const float4* a4 = (const float4*)af;
        uint2* d4 = (uint2*)afh;
        const int n4 = NATD >> 2;
        for (int i = b * 256 + t; i < n4; i += CB * 256) {
            float4 v = a4[i];
            uint2 st;
            st.x = pack_h2f(v.x, v.y);
            st.y = pack_h2f(v.z, v.w);
            d4[i] = st;
        }
    } else if (RB > 0) {
        // row_ptr: rp[s] = lower_bound(seg_i, s); rp[NAT] = E.
        // Edge e owns the disjoint range (seg[e-1], seg[e]] -> rp[.] = e.
        const int b = blk - LUTB - CB;
        for (int e = b * 256 + t; e < E; e += RB * 256) {
            int se = seg_i[e];
            int sp = (e == 0) ? -1 : seg_i[e - 1];
            for (int ss = sp + 1; ss <= se; ++ss) rp[ss] = e;
            if (e == E - 1)
                for (int ss = se + 1; ss <= NAT; ++ss) rp[ss] = E;
        }
    }
}

// v10: atom-parallel CSR. seg_i sorted => CSR rows via rp. One segment
// (mean 16 edges) per 16-lane quarter; block = 16 consecutive segments,
// whose edge range (~256, <= CAPE w/ direct-load fallback) stages
// (idx_j, lut_row) in LDS. Register accumulation over the segment, then a
// plain 2x dwordx4 store of the exclusively-owned out row.
//
// Why: R0-R5 showed the edge-parallel kernel is latency-bound (18% VALU,
// 32% fabric, occ 32%) and its flush atomics share the vmcnt stream with
// gather loads: every post-flush load wait also drains slow L2 RMW atomics.
// R2 (LDS-accum), R4 (sched_barrier), R5 (global_load_lds DMA: occ 18%,
// 64 us) all failed to fix it within the edge-parallel structure.
// v10 removes atomics entirely (12.8M -> 0), removes the 25.6 MB
// out-zero pass, removes atomic RMW line fetches, and leaves a clean
// counted gather loop with depth-1 load pipelining.
template<bool AF16>
__global__ __launch_bounds__(256) void cfconv_v10(
    const float* __restrict__ af,
    const _Float16* __restrict__ afh,
    const float* __restrict__ distances,
    const int*   __restrict__ idx_j,
    const int*   __restrict__ seg_i,
    const int*   __restrict__ rp,      // may be null -> binary search
    const _Float16* __restrict__ tab,
    float* __restrict__ out, int T, int E, int NAT)
{
    __shared__ int2 metaE[CAPE];       // (idx_j, lut_row) per staged edge 4 KB
    __shared__ int  bnd[SEGB + 1];
    const int t  = threadIdx.x;
    const int s0 = blockIdx.x * SEGB;
    const float fT = (float)T;

    if (t < SEGB + 1) {
        int key = s0 + t; if (key > NAT) key = NAT;
        if (rp) {
            bnd[t] = rp[key];
        } else {                        // fallback: lower_bound(seg_i, key)
            int lo = 0, hi = E;
            while (lo < hi) {
                int mid = (lo + hi) >> 1;
                if (seg_i[mid] < key) lo = mid + 1; else hi = mid;
            }
            bnd[t] = lo;
        }
    }
    __syncthreads();
    const int ebase = bnd[0];
    const int ecnt  = bnd[SEGB] - ebase;

    for (int i = t; i < ecnt; i += 256) {
        if (i >= CAPE) break;          // overflow edges use direct loads
        int e = ebase + i;
        int iv = (int)(distances[e] * fT);
        iv = iv < 0 ? 0 : (iv > T - 1 ? T - 1 : iv);
        metaE[i] = make_int2(idx_j[e], iv);
    }
    __syncthreads();

    const int q   = t >> 4;            // quarter 0..15 -> segment s0+q
    const int li  = t & 15;
    const int c8  = li * 8;            // 8 f16 channels owned by this lane
    int e         = bnd[q];
    const int end = bnd[q + 1];

    float s[8];
    #pragma unroll
    for (int i = 0; i < 8; ++i) s[i] = 0.f;

    h8 tb, av;
    // prologue fetch (edge e)
    if (e < end) {
        int rel = e - ebase;
        int2 m;
        if (rel < CAPE) m = metaE[rel];
        else {
            int iv = (int)(distances[e] * fT);
            iv = iv < 0 ? 0 : (iv > T - 1 ? T - 1 : iv);
            m = make_int2(idx_j[e], iv);
        }
        tb = *(const h8*)&tab[(size_t)m.y * Dm + c8];
        if (AF16) {
            av = *(const h8*)&afh[(size_t)m.x * Dm + c8];
        } else {
            float4 a0 = *(const float4*)&af[(size_t)m.x * Dm + c8];
            float4 a1 = *(const float4*)&af[(size_t)m.x * Dm + c8 + 4];
            av[0] = (_Float16)a0.x; av[1] = (_Float16)a0.y;
            av[2] = (_Float16)a0.z; av[3] = (_Float16)a0.w;
            av[4] = (_Float16)a1.x; av[5] = (_Float16)a1.y;
            av[6] = (_Float16)a1.z; av[7] = (_Float16)a1.w;
        }
    }
    // depth-1 pipelined gather loop: issue e+1's loads before e's FMAs so
    // each iteration's load latency overlaps the previous consume.
    while (e < end) {
        h8 tbc = tb, avc = av;
        int en = e + 1;
        if (en < end) {
            int rel = en - ebase;
            int2 m;
            if (rel < CAPE) m = metaE[rel];
            else {
                int iv = (int)(distances[en] * fT);
                iv = iv < 0 ? 0 : (iv > T - 1 ? T - 1 : iv);
                m = make_int2(idx_j[en], iv);
            }
            tb = *(const h8*)&tab[(size_t)m.y * Dm + c8];
            if (AF16) {
                av = *(const h8*)&afh[(size_t)m.x * Dm + c8];
            } else {
                float4 a0 = *(const float4*)&af[(size_t)m.x * Dm + c8];
                float4 a1 = *(const float4*)&af[(size_t)m.x * Dm + c8 + 4];
                av[0] = (_Float16)a0.x; av[1] = (_Float16)a0.y;
                av[2] = (_Float16)a0.z; av[3] = (_Float16)a0.w;
                av[4] = (_Float16)a1.x; av[5] = (_Float16)a1.y;
                av[6] = (_Float16)a1.z; av[7] = (_Float16)a1.w;
            }
        }
        #pragma unroll
        for (int i = 0; i < 8; ++i)   // v_fma_mix_f32: f16*f16 + f32
            s[i] = fmaf((float)tbc[i], (float)avc[i], s[i]);
        e = en;
    }

    const int sseg = s0 + q;
    if (sseg < NAT) {                  // exclusively-owned row: plain store
        float* op = &out[(size_t)sseg * Dm + c8];
        *(float4*)op       = make_float4(s[0], s[1], s[2], s[3]);
        *(float4*)(op + 4) = make_float4(s[4], s[5], s[6], s[7]);
    }
}

extern "C" void kernel_launch(void* const* d_in, const int* in_sizes, int n_in,
                              void* d_out, int out_size, void* d_ws, size_t ws_size,
                              hipStream_t stream) {
    const float* atom_features = (const float*)d_in[0];
    const float* distances     = (const float*)d_in[1];
    const int*   idx_j         = (const int*)d_in[2];
    const int*   seg_i         = (const int*)d_in[3];
    const float* centers       = (const float*)d_in[4];
    const float* gamma         = (const float*)d_in[5];
    const float* W1            = (const float*)d_in[6];
    const float* b1            = (const float*)d_in[7];
    const float* W2            = (const float*)d_in[8];
    const float* b2            = (const float*)d_in[9];

    const int E    = in_sizes[1];   // 800000
    const int NATD = out_size;      // 50000*128
    const int NAT  = NATD / Dm;     // 50000
    float* out = (float*)d_out;

    // ws layout: [tab: T*Dm*2][afh: NATD*2 (opt)][rp: (NAT+1)*4 (opt)]
    const size_t tab2048_b = (size_t)2048 * Dm * 2;
    const size_t afh_b     = (size_t)NATD * 2;
    const size_t rp_b      = (size_t)(NAT + 1) * 4;
    int T; bool af16, hasrp;
    if      (ws_size >= tab2048_b + afh_b + rp_b) { T = 2048; af16 = true;  hasrp = true;  }
    else if (ws_size >= tab2048_b + afh_b)        { T = 2048; af16 = true;  hasrp = false; }
    else if (ws_size >= tab2048_b + rp_b)         { T = 2048; af16 = false; hasrp = true;  }
    else if (ws_size >= tab2048_b)                { T = 2048; af16 = false; hasrp = false; }
    else                                          { T = 512;  af16 = false; hasrp = false; }

    char* p = (char*)d_ws;
    _Float16* tab = (_Float16*)p;
    _Float16* afh = af16 ? (_Float16*)(p + (size_t)T * Dm * 2) : nullptr;
    int* rp = hasrp
        ? (int*)(p + (size_t)T * Dm * 2 + (af16 ? afh_b : 0))
        : nullptr;

    const int LUTB = T / LUT_ROWS;      // 256 blocks at T=2048
    const int CB = af16 ? 256 : 0;
    const int RB = hasrp ? 64 : 0;
    prep_all<<<LUTB + CB + RB, 256, 0, stream>>>(
        centers, gamma, W1, b1, W2, b2, atom_features, seg_i,
        tab, afh, rp, T, LUTB, CB, RB, NATD, E, NAT);

    const int grid = (NAT + SEGB - 1) / SEGB;   // 3125
    if (af16)
        cfconv_v10<true><<<grid, 256, 0, stream>>>(
            atom_features, afh, distances, idx_j, seg_i, rp, tab, out, T, E, NAT);
    else
        cfconv_v10<false><<<grid, 256, 0, stream>>>(
            atom_features, afh, distances, idx_j, seg_i, rp, tab, out, T, E, NAT);
}